// Round 1
// baseline (437.437 us; speedup 1.0000x reference)
//
#include <hip/hip_runtime.h>
#include <stdint.h>

#define N_NODES 50000
#define N_PAD   50048      // 391 * 128
#define GQ      8
#define EE      400000
#define DIM     512
#define NE_TOT  450000     // E + N self loops
#define NBLK_SCAN 196

typedef __attribute__((ext_vector_type(8))) __bf16 bf16x8;
typedef __attribute__((ext_vector_type(4))) float f32x4;

// ---------------- helpers ----------------
__device__ __forceinline__ float bf2f(unsigned short u){ return __uint_as_float(((unsigned)u) << 16); }
__device__ __forceinline__ unsigned short f2bf(float f){
  unsigned u = __float_as_uint(f);
  return (unsigned short)((u + 0x7fffu + ((u >> 16) & 1u)) >> 16);
}
__device__ __forceinline__ float dot4(float4 a, float4 b){ return a.x*b.x + a.y*b.y + a.z*b.z + a.w*b.w; }
__device__ __forceinline__ float wredSum(float v){
#pragma unroll
  for (int o = 32; o > 0; o >>= 1) v += __shfl_xor(v, o, 64);
  return v;
}
__device__ __forceinline__ float wredMax(float v){
#pragma unroll
  for (int o = 32; o > 0; o >>= 1) v = fmaxf(v, __shfl_xor(v, o, 64));
  return v;
}
__device__ __forceinline__ void atomicMaxF(float* a, float v){
  if (v >= 0.f) atomicMax((int*)a, __float_as_int(v));
  else          atomicMin((unsigned int*)a, (unsigned int)__float_as_int(v));
}
__device__ __forceinline__ void gload_lds16(const void* g, void* l){
  __builtin_amdgcn_global_load_lds((__attribute__((address_space(1))) void*)g,
                                   (__attribute__((address_space(3))) void*)l, 16, 0, 0);
}

// ---------------- workspace layout ----------------
static constexpr size_t AL(size_t x){ return (x + 255) & ~(size_t)255; }
static constexpr size_t OFF_XBF   = 0;
static constexpr size_t OFF_HBF   = OFF_XBF   + AL((size_t)N_PAD * DIM * 2);
static constexpr size_t OFF_HCONV = OFF_HBF   + AL((size_t)N_PAD * DIM * 2);
static constexpr size_t OFF_WTBF  = OFF_HCONV + AL((size_t)N_NODES * DIM * 2);
static constexpr size_t OFF_WNT   = OFF_WTBF  + AL((size_t)DIM * DIM * 2);
static constexpr size_t OFF_W1T   = OFF_WNT   + AL((size_t)DIM * DIM * 4);
static constexpr size_t OFF_WSS   = OFF_W1T   + AL((size_t)DIM * DIM * 4);
static constexpr size_t OFF_WSD   = OFF_WSS   + AL((size_t)DIM * 4);
static constexpr size_t OFF_AS    = OFF_WSD   + AL((size_t)DIM * 4);
static constexpr size_t OFF_AD    = OFF_AS    + AL((size_t)N_NODES * 4);
static constexpr size_t OFF_GATE  = OFF_AD    + AL((size_t)N_NODES * 4);
static constexpr size_t OFF_GWS   = OFF_GATE  + AL((size_t)N_NODES * 4);
static constexpr size_t OFF_CNT   = OFF_GWS   + AL((size_t)N_NODES * 4);
static constexpr size_t OFF_FILL  = OFF_CNT   + AL((size_t)N_NODES * 4);
static constexpr size_t OFF_RS    = OFF_FILL  + AL((size_t)N_NODES * 4);
static constexpr size_t OFF_CSR   = OFF_RS    + AL((size_t)(N_NODES + 1) * 4);
static constexpr size_t OFF_BSUM  = OFF_CSR   + AL((size_t)NE_TOT * 4);
static constexpr size_t OFF_BOFF  = OFF_BSUM  + AL((size_t)NBLK_SCAN * 4);
static constexpr size_t OFF_GMAX  = OFF_BOFF  + AL((size_t)NBLK_SCAN * 4);
static constexpr size_t OFF_GSUM  = OFF_GMAX  + AL((size_t)GQ * 4);
static constexpr size_t OFF_PP    = OFF_GSUM  + AL((size_t)GQ * 4);
static constexpr size_t OFF_POOL  = OFF_PP    + AL((size_t)GQ * DIM * 4);
static constexpr size_t OFF_Z1    = OFF_POOL  + AL((size_t)GQ * DIM * 4);

// ---------------- kernels ----------------

__global__ void k_init(int* cnt, int* fill, float* gmax, float* gsum, float* pp){
  int i = blockIdx.x * 256 + threadIdx.x;
  if (i < N_NODES){ cnt[i] = 1; fill[i] = 0; }      // 1 = self-loop slot
  if (i < GQ){ gmax[i] = -__builtin_inff(); gsum[i] = 0.f; }
  if (i < GQ * DIM) pp[i] = 0.f;
}

// ws_s = W @ att_src, ws_d = W @ att_dst   (so a_s = x @ ws_s == h @ att_src)
__global__ void k_prep_w(const float* __restrict__ W, const float* __restrict__ atS,
                         const float* __restrict__ atD, float* ws_s, float* ws_d){
  int wid = threadIdx.x >> 6, lane = threadIdx.x & 63;
  int k = blockIdx.x * 4 + wid;                     // 0..511
  const float4* row = (const float4*)(W + (size_t)k * DIM);
  float4 r0 = row[lane * 2], r1 = row[lane * 2 + 1];
  const float4* s4 = (const float4*)atS;
  const float4* d4 = (const float4*)atD;
  float vs = dot4(r0, s4[lane * 2]) + dot4(r1, s4[lane * 2 + 1]);
  float vd = dot4(r0, d4[lane * 2]) + dot4(r1, d4[lane * 2 + 1]);
  vs = wredSum(vs); vd = wredSum(vd);
  if (lane == 0){ ws_s[k] = vs; ws_d[k] = vd; }
}

// 512x512 transpose, fp32 src, fp32 or bf16 dst
template<bool BF>
__global__ void k_transpose512(void* dst_, const float* __restrict__ src){
  __shared__ float tile[64][65];
  int bi = blockIdx.x & 7, bj = blockIdx.x >> 3;
  int r0 = bi * 64, c0 = bj * 64;
#pragma unroll
  for (int ii = 0; ii < 16; ++ii){
    int idx = ii * 256 + threadIdx.x;
    int r = idx >> 6, c = idx & 63;
    tile[r][c] = src[(size_t)(r0 + r) * DIM + c0 + c];
  }
  __syncthreads();
#pragma unroll
  for (int ii = 0; ii < 16; ++ii){
    int idx = ii * 256 + threadIdx.x;
    int cc = idx >> 6, rr = idx & 63;
    float v = tile[rr][cc];
    if (BF) ((unsigned short*)dst_)[(size_t)(c0 + cc) * DIM + r0 + rr] = f2bf(v);
    else    ((float*)dst_)[(size_t)(c0 + cc) * DIM + r0 + rr] = v;
  }
}

// cast x -> bf16 (zero the pad rows) and compute a_s/a_d per row
__global__ __launch_bounds__(256) void k_cast(const float* __restrict__ x,
                                              const float* __restrict__ ws_s,
                                              const float* __restrict__ ws_d,
                                              unsigned short* __restrict__ x_bf,
                                              float* __restrict__ a_s, float* __restrict__ a_d){
  int wid = threadIdx.x >> 6, lane = threadIdx.x & 63;
  size_t i = (size_t)blockIdx.x * 4 + wid;
  if (i >= N_PAD) return;
  unsigned short* orow = x_bf + i * DIM;
  if (i >= N_NODES){
    ((uint4*)orow)[lane] = make_uint4(0, 0, 0, 0);
    return;
  }
  const float4* xr = (const float4*)(x + i * DIM);
  float4 v0 = xr[lane * 2], v1 = xr[lane * 2 + 1];
  ushort4 p0 = make_ushort4(f2bf(v0.x), f2bf(v0.y), f2bf(v0.z), f2bf(v0.w));
  ushort4 p1 = make_ushort4(f2bf(v1.x), f2bf(v1.y), f2bf(v1.z), f2bf(v1.w));
  ((ushort4*)orow)[lane * 2] = p0;
  ((ushort4*)orow)[lane * 2 + 1] = p1;
  const float4* s4 = (const float4*)ws_s;
  const float4* d4 = (const float4*)ws_d;
  float vs = dot4(v0, s4[lane * 2]) + dot4(v1, s4[lane * 2 + 1]);
  float vd = dot4(v0, d4[lane * 2]) + dot4(v1, d4[lane * 2 + 1]);
  vs = wredSum(vs); vd = wredSum(vd);
  if (lane == 0){ a_s[i] = vs; a_d[i] = vd; }
}

// h = x_bf @ W (Bt = W^T, bf16), m97-style 128x128x32 MFMA tile + XOR bank swizzle
__global__ __launch_bounds__(256) void k_gemm(const unsigned short* __restrict__ A,
                                              const unsigned short* __restrict__ Bt,
                                              unsigned short* __restrict__ H){
  __shared__ unsigned short As[128 * 32];
  __shared__ unsigned short Bs[128 * 32];
  const int tid = threadIdx.x;
  const int wid = tid >> 6, lane = tid & 63, quad = lane >> 4, l16 = lane & 15;
  const int m0 = blockIdx.x * 128, n0 = blockIdx.y * 128;
  const int wm = (wid & 1) * 64, wn = (wid >> 1) * 64;
  const int qa = quad ^ ((l16 >> 1) & 3);           // swizzled chunk for reads
  f32x4 acc[4][4] = {};
  for (int kt = 0; kt < 16; ++kt){
    const int k0 = kt * 32;
    __syncthreads();
#pragma unroll
    for (int r = 0; r < 2; ++r){
      int p = r * 256 + tid;                        // 16B chunk id within tile
      int mm = p >> 2;
      int qg = (p & 3) ^ ((mm >> 1) & 3);           // swizzled source chunk
      gload_lds16(A  + (size_t)(m0 + mm) * DIM + k0 + qg * 8,
                  As + (size_t)(r * 256 + wid * 64) * 8);
      gload_lds16(Bt + (size_t)(n0 + mm) * DIM + k0 + qg * 8,
                  Bs + (size_t)(r * 256 + wid * 64) * 8);
    }
    __syncthreads();
    bf16x8 af[4], bfr[4];
#pragma unroll
    for (int f = 0; f < 4; ++f){
      af[f]  = *(const bf16x8*)(As + (wm + f * 16 + l16) * 32 + qa * 8);
      bfr[f] = *(const bf16x8*)(Bs + (wn + f * 16 + l16) * 32 + qa * 8);
    }
#pragma unroll
    for (int fm = 0; fm < 4; ++fm)
#pragma unroll
      for (int fn = 0; fn < 4; ++fn)
        acc[fm][fn] = __builtin_amdgcn_mfma_f32_16x16x32_bf16(af[fm], bfr[fn], acc[fm][fn], 0, 0, 0);
  }
#pragma unroll
  for (int fm = 0; fm < 4; ++fm){
#pragma unroll
    for (int r = 0; r < 4; ++r){
      size_t gro = (size_t)(m0 + wm + fm * 16 + quad * 4 + r) * DIM + n0 + wn + l16;
#pragma unroll
      for (int fn = 0; fn < 4; ++fn)
        H[gro + fn * 16] = f2bf(acc[fm][fn][r]);
    }
  }
}

__global__ void k_hist(const int* __restrict__ ei, int* cnt){
  int e = blockIdx.x * 256 + threadIdx.x;
  if (e < EE) atomicAdd(&cnt[ei[EE + e]], 1);
}

__global__ void k_scanA(const int* __restrict__ cnt, int* rs, int* bsum){
  __shared__ int sm[256];
  int t = threadIdx.x, i = blockIdx.x * 256 + t;
  int v = (i < N_NODES) ? cnt[i] : 0;
  sm[t] = v; __syncthreads();
#pragma unroll
  for (int off = 1; off < 256; off <<= 1){
    int nv = (t >= off) ? sm[t - off] : 0;
    __syncthreads();
    sm[t] += nv;
    __syncthreads();
  }
  if (i < N_NODES) rs[i] = sm[t] - v;
  if (t == 255) bsum[blockIdx.x] = sm[255];
}

__global__ void k_scanB(const int* __restrict__ bsum, int* boff){
  __shared__ int sm[256];
  int t = threadIdx.x;
  int v = (t < NBLK_SCAN) ? bsum[t] : 0;
  sm[t] = v; __syncthreads();
#pragma unroll
  for (int off = 1; off < 256; off <<= 1){
    int nv = (t >= off) ? sm[t - off] : 0;
    __syncthreads();
    sm[t] += nv;
    __syncthreads();
  }
  if (t < NBLK_SCAN) boff[t] = sm[t] - v;
}

__global__ void k_scanC(int* rs, const int* __restrict__ boff){
  int i = blockIdx.x * 256 + threadIdx.x;
  if (i < N_NODES) rs[i] += boff[blockIdx.x];
  if (i == 0) rs[N_NODES] = NE_TOT;
}

__global__ void k_fill_self(const int* __restrict__ rs, int* csr){
  int i = blockIdx.x * 256 + threadIdx.x;
  if (i < N_NODES) csr[rs[i]] = i;
}

__global__ void k_fill_edges(const int* __restrict__ ei, const int* __restrict__ rs,
                             int* fill, int* csr){
  int e = blockIdx.x * 256 + threadIdx.x;
  if (e < EE){
    int s = ei[e], d = ei[EE + e];
    int p = atomicAdd(&fill[d], 1);
    csr[rs[d] + 1 + p] = s;
  }
}

// one wave per dst node: segment softmax over incoming edges + weighted gather of h rows
// epilogue: +b_conv, store hconv (bf16), gate = hconv.Wg + bg
__global__ __launch_bounds__(256) void k_edge(const int* __restrict__ rs, const int* __restrict__ csr,
                                              const float* __restrict__ a_s, const float* __restrict__ a_d,
                                              const unsigned short* __restrict__ h_bf,
                                              const float* __restrict__ bconv,
                                              const float* __restrict__ Wg, const float* __restrict__ bg,
                                              unsigned short* __restrict__ hconv, float* __restrict__ gate){
  int wid = threadIdx.x >> 6, lane = threadIdx.x & 63;
  int i = blockIdx.x * 4 + wid;
  if (i >= N_NODES) return;
  int r0 = rs[i], r1 = rs[i + 1];
  float adi = a_d[i];
  float mx = -__builtin_inff();
  for (int j = r0 + lane; j < r1; j += 64){
    float e = a_s[csr[j]] + adi; e = (e > 0.f) ? e : 0.2f * e;
    mx = fmaxf(mx, e);
  }
  mx = wredMax(mx);
  float ssum = 0.f;
  for (int j = r0 + lane; j < r1; j += 64){
    float e = a_s[csr[j]] + adi; e = (e > 0.f) ? e : 0.2f * e;
    ssum += __expf(e - mx);
  }
  ssum = wredSum(ssum);
  float inv = 1.f / (ssum + 1e-16f);
  float ac0 = 0, ac1 = 0, ac2 = 0, ac3 = 0, ac4 = 0, ac5 = 0, ac6 = 0, ac7 = 0;
  for (int j = r0; j < r1; ++j){
    int s = csr[j];                                  // uniform across wave -> broadcast
    float e = a_s[s] + adi; e = (e > 0.f) ? e : 0.2f * e;
    float al = __expf(e - mx) * inv;
    const unsigned short* hr = h_bf + (size_t)s * DIM;
    ushort4 u0 = *(const ushort4*)(hr + lane * 4);
    ushort4 u1 = *(const ushort4*)(hr + 256 + lane * 4);
    ac0 += al * bf2f(u0.x); ac1 += al * bf2f(u0.y); ac2 += al * bf2f(u0.z); ac3 += al * bf2f(u0.w);
    ac4 += al * bf2f(u1.x); ac5 += al * bf2f(u1.y); ac6 += al * bf2f(u1.z); ac7 += al * bf2f(u1.w);
  }
  float4 bc0 = *(const float4*)(bconv + lane * 4);
  float4 bc1 = *(const float4*)(bconv + 256 + lane * 4);
  ac0 += bc0.x; ac1 += bc0.y; ac2 += bc0.z; ac3 += bc0.w;
  ac4 += bc1.x; ac5 += bc1.y; ac6 += bc1.z; ac7 += bc1.w;
  unsigned short* orow = hconv + (size_t)i * DIM;
  *(ushort4*)(orow + lane * 4)       = make_ushort4(f2bf(ac0), f2bf(ac1), f2bf(ac2), f2bf(ac3));
  *(ushort4*)(orow + 256 + lane * 4) = make_ushort4(f2bf(ac4), f2bf(ac5), f2bf(ac6), f2bf(ac7));
  float4 w0 = *(const float4*)(Wg + lane * 4);
  float4 w1 = *(const float4*)(Wg + 256 + lane * 4);
  float gp = ac0*w0.x + ac1*w0.y + ac2*w0.z + ac3*w0.w + ac4*w1.x + ac5*w1.y + ac6*w1.z + ac7*w1.w;
  gp = wredSum(gp);
  if (lane == 0) gate[i] = gp + bg[0];
}

__global__ void k_gmax(const float* __restrict__ gate, const int* __restrict__ batch, float* gmax){
  __shared__ float sm[8];
  int t = threadIdx.x, i = blockIdx.x * 512 + t;
  int wid = t >> 6, lane = t & 63;
  int b = (i < N_NODES) ? batch[i] : -1;
  float gv = (i < N_NODES) ? gate[i] : 0.f;
  for (int g = 0; g < GQ; ++g){
    float v = (b == g) ? gv : -__builtin_inff();
    v = wredMax(v);
    __syncthreads();
    if (lane == 0) sm[wid] = v;
    __syncthreads();
    if (t == 0){
      float m2 = sm[0];
#pragma unroll
      for (int k = 1; k < 8; ++k) m2 = fmaxf(m2, sm[k]);
      if (m2 > -__builtin_inff()) atomicMaxF(&gmax[g], m2);
    }
  }
}

__global__ void k_gsum(const float* __restrict__ gate, const int* __restrict__ batch,
                       const float* __restrict__ gmax, float* gsum){
  __shared__ float sm[8];
  int t = threadIdx.x, i = blockIdx.x * 512 + t;
  int wid = t >> 6, lane = t & 63;
  int b = (i < N_NODES) ? batch[i] : -1;
  float gv = (i < N_NODES) ? gate[i] : 0.f;
  for (int g = 0; g < GQ; ++g){
    float v = (b == g) ? __expf(gv - gmax[g]) : 0.f;
    v = wredSum(v);
    __syncthreads();
    if (lane == 0) sm[wid] = v;
    __syncthreads();
    if (t == 0){
      float s2 = 0.f;
#pragma unroll
      for (int k = 0; k < 8; ++k) s2 += sm[k];
      if (s2 != 0.f) atomicAdd(&gsum[g], s2);
    }
  }
}

__global__ void k_gvals(const float* __restrict__ gate, const int* __restrict__ batch,
                        const float* __restrict__ gmax, const float* __restrict__ gsum,
                        float* __restrict__ out_g, float* __restrict__ g_ws){
  int i = blockIdx.x * 256 + threadIdx.x;
  if (i < N_NODES){
    int b = batch[i];
    float gv = __expf(gate[i] - gmax[b]) / (gsum[b] + 1e-16f);
    out_g[i] = gv;
    g_ws[i] = gv;
  }
}

// pp[g][c] = sum_{i in graph g} g_i * hconv[i][c]
__global__ void k_pool(const unsigned short* __restrict__ hconv, const int* __restrict__ batch,
                       const float* __restrict__ g_ws, float* pp){
  int t = threadIdx.x;                     // channels 2t, 2t+1
  int base = blockIdx.x * 128;
  float ax = 0.f, ay = 0.f;
  int cur = -1;
  for (int r = 0; r < 128; ++r){
    int i = base + r;
    if (i >= N_NODES) break;
    int b = batch[i];
    float gv = g_ws[i];
    if (b != cur){
      if (cur >= 0){
        atomicAdd(&pp[cur * DIM + 2 * t], ax);
        atomicAdd(&pp[cur * DIM + 2 * t + 1], ay);
      }
      ax = ay = 0.f; cur = b;
    }
    unsigned u = *(const unsigned*)(hconv + (size_t)i * DIM + 2 * t);
    ax += gv * bf2f((unsigned short)(u & 0xffffu));
    ay += gv * bf2f((unsigned short)(u >> 16));
  }
  if (cur >= 0){
    atomicAdd(&pp[cur * DIM + 2 * t], ax);
    atomicAdd(&pp[cur * DIM + 2 * t + 1], ay);
  }
}

// dst[g][j] = (relu?)(src[g][:] . WT[j][:] + bias[j]) for the tiny head GEMMs
template<bool RELU>
__global__ void k_head_mm(const float* __restrict__ src, const float* __restrict__ WT,
                          const float* __restrict__ bias, float* dst){
  __shared__ float sp[GQ * DIM];
  int t = threadIdx.x;
  for (int idx = t; idx < GQ * DIM; idx += 256) sp[idx] = src[idx];
  __syncthreads();
  int wid = t >> 6, lane = t & 63;
  int j = blockIdx.x * 4 + wid;
  const float4* wr = (const float4*)(WT + (size_t)j * DIM);
  float4 w0 = wr[lane * 2], w1 = wr[lane * 2 + 1];
  float bj = bias[j];
#pragma unroll
  for (int g = 0; g < GQ; ++g){
    const float* pg = sp + g * DIM + lane * 8;
    float s = w0.x*pg[0] + w0.y*pg[1] + w0.z*pg[2] + w0.w*pg[3]
            + w1.x*pg[4] + w1.y*pg[5] + w1.z*pg[6] + w1.w*pg[7];
    s = wredSum(s);
    if (lane == 0){
      s += bj;
      if (RELU) s = fmaxf(s, 0.f);
      dst[g * DIM + j] = s;
    }
  }
}

__global__ void k_head_out(const float* __restrict__ z1, const float* __restrict__ W2,
                           const float* __restrict__ b2, float* out){
  int wid = threadIdx.x >> 6, lane = threadIdx.x & 63;   // 8 waves = 8 graphs
  const float4* zr = (const float4*)(z1 + (size_t)wid * DIM);
  const float4* w4 = (const float4*)W2;
  float s = dot4(zr[lane * 2], w4[lane * 2]) + dot4(zr[lane * 2 + 1], w4[lane * 2 + 1]);
  s = wredSum(s);
  if (lane == 0) out[wid] = 1.f / (1.f + __expf(-(s + b2[0])));
}

// ---------------- launch ----------------
extern "C" void kernel_launch(void* const* d_in, const int* in_sizes, int n_in,
                              void* d_out, int out_size, void* d_ws, size_t ws_size,
                              hipStream_t stream){
  (void)in_sizes; (void)n_in; (void)out_size; (void)ws_size;
  const float* x   = (const float*)d_in[0];
  const int*   ei  = (const int*)d_in[1];
  const int*   bat = (const int*)d_in[2];
  const float* W   = (const float*)d_in[3];
  const float* atS = (const float*)d_in[4];
  const float* atD = (const float*)d_in[5];
  const float* bcv = (const float*)d_in[6];
  const float* Wg  = (const float*)d_in[7];
  const float* bg  = (const float*)d_in[8];
  const float* Wn  = (const float*)d_in[9];
  const float* bn  = (const float*)d_in[10];
  const float* W1  = (const float*)d_in[11];
  const float* b1  = (const float*)d_in[12];
  const float* W2  = (const float*)d_in[13];
  const float* b2  = (const float*)d_in[14];
  float* out = (float*)d_out;
  char* ws = (char*)d_ws;

  unsigned short* x_bf  = (unsigned short*)(ws + OFF_XBF);
  unsigned short* h_bf  = (unsigned short*)(ws + OFF_HBF);
  unsigned short* hconv = (unsigned short*)(ws + OFF_HCONV);
  unsigned short* Wt_bf = (unsigned short*)(ws + OFF_WTBF);
  float* WnT  = (float*)(ws + OFF_WNT);
  float* W1T  = (float*)(ws + OFF_W1T);
  float* ws_s = (float*)(ws + OFF_WSS);
  float* ws_d = (float*)(ws + OFF_WSD);
  float* a_s  = (float*)(ws + OFF_AS);
  float* a_d  = (float*)(ws + OFF_AD);
  float* gate = (float*)(ws + OFF_GATE);
  float* g_ws = (float*)(ws + OFF_GWS);
  int* cnt  = (int*)(ws + OFF_CNT);
  int* fill = (int*)(ws + OFF_FILL);
  int* rs   = (int*)(ws + OFF_RS);
  int* csr  = (int*)(ws + OFF_CSR);
  int* bsum = (int*)(ws + OFF_BSUM);
  int* boff = (int*)(ws + OFF_BOFF);
  float* gmax = (float*)(ws + OFF_GMAX);
  float* gsum = (float*)(ws + OFF_GSUM);
  float* pp   = (float*)(ws + OFF_PP);
  float* pool = (float*)(ws + OFF_POOL);
  float* z1   = (float*)(ws + OFF_Z1);

  hipLaunchKernelGGL(k_init, dim3(NBLK_SCAN), dim3(256), 0, stream, cnt, fill, gmax, gsum, pp);
  hipLaunchKernelGGL((k_transpose512<true>),  dim3(64), dim3(256), 0, stream, (void*)Wt_bf, W);
  hipLaunchKernelGGL((k_transpose512<false>), dim3(64), dim3(256), 0, stream, (void*)WnT, Wn);
  hipLaunchKernelGGL((k_transpose512<false>), dim3(64), dim3(256), 0, stream, (void*)W1T, W1);
  hipLaunchKernelGGL(k_prep_w, dim3(128), dim3(256), 0, stream, W, atS, atD, ws_s, ws_d);
  hipLaunchKernelGGL(k_cast, dim3(N_PAD / 4), dim3(256), 0, stream, x, ws_s, ws_d, x_bf, a_s, a_d);
  hipLaunchKernelGGL(k_gemm, dim3(N_PAD / 128, 4), dim3(256), 0, stream, x_bf, Wt_bf, h_bf);
  hipLaunchKernelGGL(k_hist, dim3((EE + 255) / 256), dim3(256), 0, stream, ei, cnt);
  hipLaunchKernelGGL(k_scanA, dim3(NBLK_SCAN), dim3(256), 0, stream, cnt, rs, bsum);
  hipLaunchKernelGGL(k_scanB, dim3(1), dim3(256), 0, stream, bsum, boff);
  hipLaunchKernelGGL(k_scanC, dim3(NBLK_SCAN), dim3(256), 0, stream, rs, boff);
  hipLaunchKernelGGL(k_fill_self, dim3(NBLK_SCAN), dim3(256), 0, stream, rs, csr);
  hipLaunchKernelGGL(k_fill_edges, dim3((EE + 255) / 256), dim3(256), 0, stream, ei, rs, fill, csr);
  hipLaunchKernelGGL(k_edge, dim3(N_NODES / 4), dim3(256), 0, stream,
                     rs, csr, a_s, a_d, h_bf, bcv, Wg, bg, hconv, gate);
  hipLaunchKernelGGL(k_gmax, dim3(98), dim3(512), 0, stream, gate, bat, gmax);
  hipLaunchKernelGGL(k_gsum, dim3(98), dim3(512), 0, stream, gate, bat, gmax, gsum);
  hipLaunchKernelGGL(k_gvals, dim3(NBLK_SCAN), dim3(256), 0, stream, gate, bat, gmax, gsum, out + GQ, g_ws);
  hipLaunchKernelGGL(k_pool, dim3((N_NODES + 127) / 128), dim3(256), 0, stream, hconv, bat, g_ws, pp);
  hipLaunchKernelGGL((k_head_mm<false>), dim3(128), dim3(256), 0, stream, pp, WnT, bn, pool);
  hipLaunchKernelGGL((k_head_mm<true>),  dim3(128), dim3(256), 0, stream, pool, W1T, b1, z1);
  hipLaunchKernelGGL(k_head_out, dim3(1), dim3(512), 0, stream, z1, W2, b2, out);
}